// Round 3
// baseline (307.019 us; speedup 1.0000x reference)
//
#include <hip/hip_runtime.h>
#include <math.h>
#include <stdint.h>

#define NROWS 16384
#define NCOLS 1000
#define NMAT  5
#define RPB   16                        // rows per block (one wave per block)
#define NBLK  (NROWS / RPB)             // 1024 blocks -> 4 per CU (LDS-bound)
#define NINF  (-INFINITY)

// Async global->LDS, 16B per lane. LDS dest is wave-uniform base + lane*16.
__device__ __forceinline__ void gld16(const float4* g, float4* l) {
    __builtin_amdgcn_global_load_lds(
        (const __attribute__((address_space(1))) void*)(uintptr_t)g,
        (__attribute__((address_space(3))) void*)(uint32_t)(uintptr_t)l,
        16, 0, 0);
}

// Stage one row (5 matrices x 4000 B) into buf: 20 DMA ops, no VGPR cost.
// Chunks 0..2 full (64 lanes x 16B); chunk 3 covers bytes 3072..3999 (58 lanes).
#define PREFETCH(row, buf) do {                                               \
    _Pragma("unroll")                                                         \
    for (int _m = 0; _m < NMAT; ++_m) {                                       \
        const float4* _g = (const float4*)(mats[_m] + (size_t)(row) * NCOLS); \
        _Pragma("unroll")                                                     \
        for (int _s = 0; _s < 3; ++_s)                                        \
            gld16(_g + _s * 64 + lane, &buf[_m][_s * 64]);                    \
    }                                                                         \
    if (lane < 58) {                                                          \
        _Pragma("unroll")                                                     \
        for (int _m = 0; _m < NMAT; ++_m) {                                   \
            const float4* _g = (const float4*)(mats[_m] + (size_t)(row) * NCOLS); \
            gld16(_g + 192 + lane, &buf[_m][192]);                            \
        }                                                                     \
    }                                                                         \
} while (0)

#define UPD(m, x) { float _mn = fminf(t1[m], (x)); t1[m] = fmaxf(t1[m], (x)); \
                    t2[m] = fmaxf(t2[m], _mn); }

// Reduce one staged row: per-lane top-2, interleaved butterfly, margins +
// softmax (all lanes redundantly -> no serial tail), output write.
#define PROCESS(buf, row) do {                                                \
    const int _t = targets[row];                                              \
    float t1[NMAT], t2[NMAT];                                                 \
    _Pragma("unroll")                                                         \
    for (int _m = 0; _m < NMAT; ++_m) {                                       \
        t1[_m] = NINF; t2[_m] = NINF;                                         \
        _Pragma("unroll")                                                     \
        for (int _s = 0; _s < 4; ++_s) {                                      \
            float4 _x = buf[_m][_s * 64 + lane];                              \
            if (_s == 3 && lane >= 58) {                                      \
                _x.x = NINF; _x.y = NINF; _x.z = NINF; _x.w = NINF;           \
            }                                                                 \
            UPD(_m, _x.x) UPD(_m, _x.y) UPD(_m, _x.z) UPD(_m, _x.w)          \
        }                                                                     \
    }                                                                         \
    _Pragma("unroll")                                                         \
    for (int _off = 32; _off > 0; _off >>= 1) {                               \
        float _a1[NMAT], _a2[NMAT];                                           \
        _Pragma("unroll")                                                     \
        for (int _m = 0; _m < NMAT; ++_m) {                                   \
            _a1[_m] = __shfl_xor(t1[_m], _off);                               \
            _a2[_m] = __shfl_xor(t2[_m], _off);                               \
        }                                                                     \
        _Pragma("unroll")                                                     \
        for (int _m = 0; _m < NMAT; ++_m) {                                   \
            float _mn = fminf(t1[_m], _a1[_m]);                               \
            t1[_m] = fmaxf(t1[_m], _a1[_m]);                                  \
            t2[_m] = fmaxf(fmaxf(t2[_m], _a2[_m]), _mn);                      \
        }                                                                     \
    }                                                                         \
    const float* _bf = (const float*)&buf[0][0];                              \
    float _mg[NMAT];                                                          \
    _Pragma("unroll")                                                         \
    for (int _m = 0; _m < NMAT; ++_m) {                                       \
        const float _tg = _bf[_m * 1024 + _t];  /* broadcast LDS read */      \
        _mg[_m] = (_tg == t1[_m]) ? (t1[_m] - t2[_m]) : 0.0f;                 \
    }                                                                         \
    float _mx = _mg[0];                                                       \
    _Pragma("unroll")                                                         \
    for (int _m = 1; _m < NMAT; ++_m) _mx = fmaxf(_mx, _mg[_m]);              \
    float _e[NMAT], _ss = 0.0f;                                               \
    _Pragma("unroll")                                                         \
    for (int _m = 0; _m < NMAT; ++_m) {                                       \
        _e[_m] = __expf((_mg[_m] - _mx) * 0.5f); _ss += _e[_m];               \
    }                                                                         \
    const float _inv = 1.0f / _ss;                                            \
    float _wv = _e[0] * _inv;                                                 \
    if (lane == 1) _wv = _e[1] * _inv;                                        \
    if (lane == 2) _wv = _e[2] * _inv;                                        \
    if (lane == 3) _wv = _e[3] * _inv;                                        \
    if (lane == 4) _wv = _e[4] * _inv;                                        \
    if (lane < NMAT) out[1 + (size_t)(row) * NMAT + lane] = _wv;              \
    bmax = fmaxf(bmax, fmaxf(fmaxf(t1[0], t1[1]), fmaxf(t1[2], t1[3])));      \
} while (0)

__global__ __launch_bounds__(64) void fused_kernel(
    const float* __restrict__ o0, const float* __restrict__ o1,
    const float* __restrict__ o2, const float* __restrict__ o3,
    const float* __restrict__ o4, const int* __restrict__ targets,
    float* __restrict__ out, float* __restrict__ blockmax)
{
    const int lane = threadIdx.x;              // block = 1 wave
    const int row0 = blockIdx.x * RPB;

    __shared__ float4 bufA[NMAT][256];         // 20,480 B (4096 B per matrix)
    __shared__ float4 bufB[NMAT][256];         // distinct objects: lets the
                                               // waitcnt pass disambiguate DMA
    const float* mats[NMAT] = {o0, o1, o2, o3, o4};
    float bmax = NINF;

    PREFETCH(row0, bufA);
    for (int i = 0; i < RPB; i += 2) {
        PREFETCH(row0 + i + 1, bufB);
        // leave the 20 newest (bufB) in flight; guarantees bufA's retired
        asm volatile("s_waitcnt vmcnt(20)" ::: "memory");
        PROCESS(bufA, row0 + i);
        if (i + 2 < RPB) {
            PREFETCH(row0 + i + 2, bufA);
            asm volatile("s_waitcnt vmcnt(20)" ::: "memory");
        } else {
            asm volatile("s_waitcnt vmcnt(0)" ::: "memory");
        }
        PROCESS(bufB, row0 + i + 1);
    }
    if (lane == 0) blockmax[blockIdx.x] = bmax;
}

__global__ __launch_bounds__(256) void reduce_kernel(
    const float* __restrict__ blockmax, float* __restrict__ out)
{
    __shared__ float red[256];
    float mm = NINF;
    for (int k = threadIdx.x; k < NBLK; k += 256)
        mm = fmaxf(mm, blockmax[k]);
    red[threadIdx.x] = mm;
    __syncthreads();
    #pragma unroll
    for (int s = 128; s > 0; s >>= 1) {
        if (threadIdx.x < s)
            red[threadIdx.x] = fmaxf(red[threadIdx.x], red[threadIdx.x + s]);
        __syncthreads();
    }
    if (threadIdx.x == 0) out[0] = red[0];
}

extern "C" void kernel_launch(void* const* d_in, const int* in_sizes, int n_in,
                              void* d_out, int out_size, void* d_ws, size_t ws_size,
                              hipStream_t stream) {
    const float* o0 = (const float*)d_in[0];
    const float* o1 = (const float*)d_in[1];
    const float* o2 = (const float*)d_in[2];
    const float* o3 = (const float*)d_in[3];
    const float* o4 = (const float*)d_in[4];
    const int*   tg = (const int*)d_in[5];
    float* out = (float*)d_out;

    float* blockmax = (float*)d_ws;            // NBLK floats (4 KB)

    fused_kernel<<<NBLK, 64, 0, stream>>>(o0, o1, o2, o3, o4, tg,
                                          out, blockmax);
    reduce_kernel<<<1, 256, 0, stream>>>(blockmax, out);
}